// Round 7
// baseline (170.560 us; speedup 1.0000x reference)
//
#include <hip/hip_runtime.h>

// ---------------- problem constants ----------------
#define MAX_IN   1024
#define MAX_OUT  4096
#define LOW_RANK 64
#define N_ARCH   16
#define HYP_HID  128
#define BATCH_M  8192   // 4 * 2048

typedef __attribute__((ext_vector_type(8))) short short8;     // 8 x bf16
typedef __attribute__((ext_vector_type(16))) float f32x16;    // 32x32 acc

// round-to-nearest-even fp32 -> bf16
__device__ __forceinline__ unsigned short f2bf(float f) {
  union { float f; unsigned int u; } c; c.f = f;
  unsigned int r = c.u + 0x7fffu + ((c.u >> 16) & 1u);
  return (unsigned short)(r >> 16);
}

__device__ __forceinline__ void gload16(const unsigned short* g, unsigned short* l) {
  __builtin_amdgcn_global_load_lds(
      (const __attribute__((address_space(1))) unsigned int*)(g),
      (__attribute__((address_space(3))) unsigned int*)(l), 16, 0, 0);
}

// ---------------- kernel 1: X fp32 -> bf16 ----------------
__global__ __launch_bounds__(256) void convert_x(const float* __restrict__ in,
                                                 unsigned short* __restrict__ out) {
  size_t i = (size_t)blockIdx.x * 256 + threadIdx.x;
  float4 v = *(const float4*)(in + i * 4);
  ushort4 o;
  o.x = f2bf(v.x); o.y = f2bf(v.y); o.z = f2bf(v.z); o.w = f2bf(v.w);
  *(ushort4*)(out + i * 4) = o;
}

// ---------------- kernel 2: fused prep  W = base + (hyp MLP) @ lr ----------------
// 512 blocks x 256 thr. Block handles 8 W-rows: computes h (redundant),
// its own 512 left-rows (hyp_w2 HBM read), then W rows.
__global__ __launch_bounds__(256) void build_w_fused(
    const float* __restrict__ w1, const float* __restrict__ b1,
    const float* __restrict__ e,
    const float* __restrict__ hyp_w2, const float* __restrict__ hyp_b2,
    const float* __restrict__ base_w, const float* __restrict__ lrf,
    unsigned short* __restrict__ Wbf) {
  __shared__ float hs[HYP_HID];
  __shared__ float lefts[8 * LOW_RANK];
  const int tid = threadIdx.x;
  const int o0 = blockIdx.x * 8;

  if (tid < HYP_HID) {
    const float4* wr = (const float4*)(w1 + tid * N_ARCH);
    float s = b1[tid];
#pragma unroll
    for (int c = 0; c < 4; c++) {
      float4 wv = wr[c];
      float4 ev = *(const float4*)(e + c * 4);
      s += wv.x * ev.x + wv.y * ev.y + wv.z * ev.z + wv.w * ev.w;
    }
    hs[tid] = fmaxf(s, 0.0f);
  }
  __syncthreads();

  const int lane = tid & 63;
  const int w = tid >> 6;
  const int g = lane >> 3, gl = lane & 7;
  float4 hf[4];
#pragma unroll
  for (int c = 0; c < 4; c++) hf[c] = *(const float4*)(hs + c * 32 + gl * 4);
#pragma unroll 4
  for (int it = 0; it < 16; ++it) {
    const int rl = w * 128 + it * 8 + g;    // 0..511
    const float* rp = hyp_w2 + (size_t)(o0 * LOW_RANK + rl) * HYP_HID;
    float s = 0.f;
#pragma unroll
    for (int c = 0; c < 4; c++) {
      float4 v = *(const float4*)(rp + c * 32 + gl * 4);
      s += v.x * hf[c].x + v.y * hf[c].y + v.z * hf[c].z + v.w * hf[c].w;
    }
    s += __shfl_xor(s, 4);
    s += __shfl_xor(s, 2);
    s += __shfl_xor(s, 1);
    if (gl == 0) lefts[rl] = s + hyp_b2[o0 * LOW_RANK + rl];
  }
  __syncthreads();

#pragma unroll
  for (int kk = 0; kk < 4; kk++) {
    const int k = kk * 256 + tid;
    float acc[8];
#pragma unroll
    for (int oi = 0; oi < 8; oi++) acc[oi] = base_w[(size_t)(o0 + oi) * MAX_IN + k];
    for (int r = 0; r < LOW_RANK; r++) {
      float lv = lrf[r * MAX_IN + k];
#pragma unroll
      for (int oi = 0; oi < 8; oi++) acc[oi] += lefts[oi * LOW_RANK + r] * lv;
    }
#pragma unroll
    for (int oi = 0; oi < 8; oi++)
      Wbf[(size_t)(o0 + oi) * MAX_IN + k] = f2bf(acc[oi]);
  }
}

// ---------------- kernel 3: GEMM  C = Xbf @ Wbf^T + bias ----------------
// 256x128 tile, 4 waves (2M x 2N), wave-tile 128x64 of 32x32x16 frags.
// BK=32, 3 LDS buffers (72 KB) -> 2 blocks/CU co-resident (the overlap lever).
// Distance-2 staging, one vmcnt(6)+barrier per iter.
// Swizzle: 64-B rows, 16B-chunk c' = c ^ ((r>>1)&3); staged via inverse-
// swizzled GLOBAL source + linear gload_lds dest.
__global__ __launch_bounds__(256, 2) void gemm_kernel(
    const unsigned short* __restrict__ A,   // [M][K] bf16
    const unsigned short* __restrict__ B,   // [N][K] bf16 (= W)
    const float* __restrict__ bias,         // [N]
    float* __restrict__ C) {                // [M][N] fp32
  constexpr int K = MAX_IN;
  constexpr int N = MAX_OUT;
  constexpr int ABUF = 256 * 32;           // 8192 ushorts (16 KB)
  constexpr int TBUF = ABUF + 128 * 32;    // 12288 ushorts (24 KB)
  constexpr int NT = K / 32;               // 32
  __shared__ __align__(16) unsigned short lds[3 * TBUF];  // 72 KB

  const int tid = threadIdx.x;             // 0..255
  const int lane = tid & 63;
  const int w = tid >> 6;                  // wave 0..3
  const int wm = w >> 1, wn = w & 1;       // 2M x 2N
  const int l31 = lane & 31, hi2 = lane >> 5;

  // XCD swizzle: 1024 wgs, XCD x gets 128 contiguous = 4 N-panels x all M
  const int orig = blockIdx.x;
  const int wg = (orig & 7) * 128 + (orig >> 3);
  const int bm = (wg & 31) * 256;          // 32 M-tiles
  const int bn = (wg >> 5) * 128;          // 32 N-tiles

  // ---- staging source (inverse swizzle): thread covers row tid>>2 (+64j),
  // LDS slot chunk tid&3, logical chunk c = (tid&3) ^ ((tid>>3)&3)
  const int cst = (tid & 3) ^ ((tid >> 3) & 3);
  const unsigned short* Asrc = A + (size_t)(bm + (tid >> 2)) * K + cst * 8;
  const unsigned short* Bsrc = B + (size_t)(bn + (tid >> 2)) * K + cst * 8;

  // ---- fragment read offsets (ushort units), ks=0; ks=1 = ^16 ----
  int aoff[4], boff[2];
#pragma unroll
  for (int m = 0; m < 4; m++) {
    const int r = wm * 128 + m * 32 + l31;
    aoff[m] = r * 32 + ((hi2 ^ ((r >> 1) & 3)) * 8);
  }
#pragma unroll
  for (int n = 0; n < 2; n++) {
    const int r = wn * 64 + n * 32 + l31;
    boff[n] = ABUF + r * 32 + ((hi2 ^ ((r >> 1) & 3)) * 8);
  }

  f32x16 acc[4][2];
#pragma unroll
  for (int m = 0; m < 4; m++)
#pragma unroll
    for (int n = 0; n < 2; n++)
#pragma unroll
      for (int j = 0; j < 16; j++) acc[m][n][j] = 0.f;

#define STAGE(p, kt)                                                      \
  do {                                                                    \
    unsigned short* lb_ = &lds[(p) * TBUF];                               \
    _Pragma("unroll")                                                     \
    for (int j = 0; j < 4; j++)                                           \
      gload16(Asrc + (size_t)(64 * j) * K + (kt) * 32,                    \
              &lb_[j * 2048 + tid * 8]);                                  \
    _Pragma("unroll")                                                     \
    for (int j = 0; j < 2; j++)                                           \
      gload16(Bsrc + (size_t)(64 * j) * K + (kt) * 32,                    \
              &lb_[ABUF + j * 2048 + tid * 8]);                           \
  } while (0)

  // prologue: tiles 0,1 in flight; wait tile 0 (tile 1's 6 loads may fly)
  STAGE(0, 0);
  STAGE(1, 1);
  asm volatile("s_waitcnt vmcnt(6)" ::: "memory");
  __builtin_amdgcn_s_barrier();
  __builtin_amdgcn_sched_barrier(0);

  int p = 0;
  for (int t = 0; t < NT; ++t) {
    if (t + 2 < NT) {
      const int pn = (p + 2 >= 3) ? p - 1 : p + 2;
      STAGE(pn, t + 2);
    }
    const unsigned short* lb = &lds[p * TBUF];
    short8 a0[4], a1[4], b0[2], b1[2];
#pragma unroll
    for (int m = 0; m < 4; m++) {
      a0[m] = *(const short8*)&lb[aoff[m]];
      a1[m] = *(const short8*)&lb[aoff[m] ^ 16];
    }
#pragma unroll
    for (int n = 0; n < 2; n++) {
      b0[n] = *(const short8*)&lb[boff[n]];
      b1[n] = *(const short8*)&lb[boff[n] ^ 16];
    }
    __builtin_amdgcn_s_setprio(1);
#pragma unroll
    for (int m = 0; m < 4; m++)
#pragma unroll
      for (int n = 0; n < 2; n++)
        acc[m][n] = __builtin_amdgcn_mfma_f32_32x32x16_bf16(a0[m], b0[n], acc[m][n], 0, 0, 0);
#pragma unroll
    for (int m = 0; m < 4; m++)
#pragma unroll
      for (int n = 0; n < 2; n++)
        acc[m][n] = __builtin_amdgcn_mfma_f32_32x32x16_bf16(a1[m], b1[n], acc[m][n], 0, 0, 0);
    __builtin_amdgcn_s_setprio(0);
    if (t + 2 < NT) {
      asm volatile("s_waitcnt vmcnt(6)" ::: "memory");   // tile t+1 landed
    } else if (t + 1 < NT) {
      asm volatile("s_waitcnt vmcnt(0)" ::: "memory");
    }
    if (t + 1 < NT) {
      __builtin_amdgcn_s_barrier();
      __builtin_amdgcn_sched_barrier(0);
    }
    p = (p + 1 == 3) ? 0 : p + 1;
  }
#undef STAGE

  // ---- epilogue: 32x32 C/D layout col=lane&31, row=(reg&3)+8*(reg>>2)+4*hi2
  float bv[2];
#pragma unroll
  for (int n = 0; n < 2; n++) bv[n] = bias[bn + wn * 64 + n * 32 + l31];
#pragma unroll
  for (int m = 0; m < 4; m++) {
#pragma unroll
    for (int n = 0; n < 2; n++) {
      const int gc = bn + wn * 64 + n * 32 + l31;
#pragma unroll
      for (int rg = 0; rg < 4; rg++) {
#pragma unroll
        for (int rr = 0; rr < 4; rr++) {
          const int gr = bm + wm * 128 + m * 32 + rr + rg * 8 + hi2 * 4;
          C[(size_t)gr * N + gc] = acc[m][n][rg * 4 + rr] + bv[n];
        }
      }
    }
  }
}

// ---------------- launcher ----------------
extern "C" void kernel_launch(void* const* d_in, const int* in_sizes, int n_in,
                              void* d_out, int out_size, void* d_ws, size_t ws_size,
                              hipStream_t stream) {
  const float* x      = (const float*)d_in[0];
  const float* embed  = (const float*)d_in[1];
  const float* base_w = (const float*)d_in[2];
  const float* base_b = (const float*)d_in[3];
  const float* lrf    = (const float*)d_in[4];
  const float* w1     = (const float*)d_in[5];
  const float* b1     = (const float*)d_in[6];
  const float* w2     = (const float*)d_in[7];
  const float* b2     = (const float*)d_in[8];
  float* out = (float*)d_out;

  char* ws = (char*)d_ws;
  unsigned short* Xbf = (unsigned short*)ws;                              // 16 MB
  unsigned short* Wbf = (unsigned short*)(ws + (size_t)BATCH_M * MAX_IN * 2);  // 8 MB

  hipLaunchKernelGGL(convert_x, dim3(BATCH_M * MAX_IN / 1024), dim3(256), 0, stream, x, Xbf);
  hipLaunchKernelGGL(build_w_fused, dim3(MAX_OUT / 8), dim3(256), 0, stream,
                     w1, b1, embed, w2, b2, base_w, lrf, Wbf);
  hipLaunchKernelGGL(gemm_kernel, dim3((BATCH_M / 256) * (MAX_OUT / 128)), dim3(256), 0, stream,
                     Xbf, Wbf, base_b, out);
}

// Round 8
// 150.350 us; speedup vs baseline: 1.1344x; 1.1344x over previous
//
#include <hip/hip_runtime.h>

// ---------------- problem constants ----------------
#define MAX_IN   1024
#define MAX_OUT  4096
#define LOW_RANK 64
#define N_ARCH   16
#define HYP_HID  128
#define BATCH_M  8192   // 4 * 2048

typedef __attribute__((ext_vector_type(8))) short short8;   // 8 x bf16
typedef __attribute__((ext_vector_type(4))) float f32x4;

// round-to-nearest-even fp32 -> bf16
__device__ __forceinline__ unsigned short f2bf(float f) {
  union { float f; unsigned int u; } c; c.f = f;
  unsigned int r = c.u + 0x7fffu + ((c.u >> 16) & 1u);
  return (unsigned short)(r >> 16);
}

__device__ __forceinline__ void gload16(const unsigned short* g, unsigned short* l) {
  __builtin_amdgcn_global_load_lds(
      (const __attribute__((address_space(1))) unsigned int*)(g),
      (__attribute__((address_space(3))) unsigned int*)(l), 16, 0, 0);
}

// ---------------- kernel 1: X fp32 -> bf16 ----------------
__global__ __launch_bounds__(256) void convert_x(const float* __restrict__ in,
                                                 unsigned short* __restrict__ out) {
  size_t i = (size_t)blockIdx.x * 256 + threadIdx.x;
  float4 v = *(const float4*)(in + i * 4);
  ushort4 o;
  o.x = f2bf(v.x); o.y = f2bf(v.y); o.z = f2bf(v.z); o.w = f2bf(v.w);
  *(ushort4*)(out + i * 4) = o;
}

// ---------------- kernel 2: fused prep  W = base + (hyp MLP) @ lr ----------------
__global__ __launch_bounds__(256) void build_w_fused(
    const float* __restrict__ w1, const float* __restrict__ b1,
    const float* __restrict__ e,
    const float* __restrict__ hyp_w2, const float* __restrict__ hyp_b2,
    const float* __restrict__ base_w, const float* __restrict__ lrf,
    unsigned short* __restrict__ Wbf) {
  __shared__ float hs[HYP_HID];
  __shared__ float lefts[8 * LOW_RANK];
  const int tid = threadIdx.x;
  const int o0 = blockIdx.x * 8;

  if (tid < HYP_HID) {
    const float4* wr = (const float4*)(w1 + tid * N_ARCH);
    float s = b1[tid];
#pragma unroll
    for (int c = 0; c < 4; c++) {
      float4 wv = wr[c];
      float4 ev = *(const float4*)(e + c * 4);
      s += wv.x * ev.x + wv.y * ev.y + wv.z * ev.z + wv.w * ev.w;
    }
    hs[tid] = fmaxf(s, 0.0f);
  }
  __syncthreads();

  const int lane = tid & 63;
  const int w = tid >> 6;
  const int g = lane >> 3, gl = lane & 7;
  float4 hf[4];
#pragma unroll
  for (int c = 0; c < 4; c++) hf[c] = *(const float4*)(hs + c * 32 + gl * 4);
#pragma unroll 4
  for (int it = 0; it < 16; ++it) {
    const int rl = w * 128 + it * 8 + g;    // 0..511
    const float* rp = hyp_w2 + (size_t)(o0 * LOW_RANK + rl) * HYP_HID;
    float s = 0.f;
#pragma unroll
    for (int c = 0; c < 4; c++) {
      float4 v = *(const float4*)(rp + c * 32 + gl * 4);
      s += v.x * hf[c].x + v.y * hf[c].y + v.z * hf[c].z + v.w * hf[c].w;
    }
    s += __shfl_xor(s, 4);
    s += __shfl_xor(s, 2);
    s += __shfl_xor(s, 1);
    if (gl == 0) lefts[rl] = s + hyp_b2[o0 * LOW_RANK + rl];
  }
  __syncthreads();

#pragma unroll
  for (int kk = 0; kk < 4; kk++) {
    const int k = kk * 256 + tid;
    float acc[8];
#pragma unroll
    for (int oi = 0; oi < 8; oi++) acc[oi] = base_w[(size_t)(o0 + oi) * MAX_IN + k];
    for (int r = 0; r < LOW_RANK; r++) {
      float lv = lrf[r * MAX_IN + k];
#pragma unroll
      for (int oi = 0; oi < 8; oi++) acc[oi] += lefts[oi * LOW_RANK + r] * lv;
    }
#pragma unroll
    for (int oi = 0; oi < 8; oi++)
      Wbf[(size_t)(o0 + oi) * MAX_IN + k] = f2bf(acc[oi]);
  }
}

// ---------------- kernel 3: m201-style phase-split GEMM ----------------
// 256x256 tile, BK=64, NT=16, 8 waves (2M x 4N), wave tile 128x64, 16x16x32.
// 4 phases/K-tile, each: {ds_reads | stage 1 half-tile} -> barrier ->
// lgkmcnt(0)+sched_barrier -> setprio(1) -> 16 MFMA -> setprio(0) -> barrier.
// vmcnt(4) once per K-tile (phase 3), never 0 until tail.
// Stage rotation: A-halves(t+1) at P0/P1 (slot freed end of t-1);
// B-halves(t+2) at P2/P3 (B reads of t complete at P1 post-MFMA barrier).
// Swizzle (R6-verified, 0 conflicts): row r (128 B), chunk c' = c ^ (r&7);
// staged via inverse-swizzled GLOBAL source + linear gload_lds dest.
__global__ __launch_bounds__(512, 2) void gemm_kernel(
    const unsigned short* __restrict__ A,   // [M][K] bf16
    const unsigned short* __restrict__ B,   // [N][K] bf16 (= W)
    const float* __restrict__ bias,         // [N]
    float* __restrict__ C) {                // [M][N] fp32
  constexpr int K = MAX_IN;
  constexpr int N = MAX_OUT;
  constexpr int SLOT = 32768;              // ushorts per slot (A 16K + B 16K)
  constexpr int BOFF = 16384;
  constexpr int NT = K / 64;               // 16
  __shared__ __align__(16) unsigned short lds[2 * SLOT];  // 128 KB

  const int tid = threadIdx.x;             // 0..511
  const int lane = tid & 63;
  const int w = tid >> 6;                  // wave 0..7
  const int wm = w >> 2, wn = w & 3;       // 2M x 4N
  const int fl = lane & 15, hi = lane >> 4;

  // XCD-aware macro-tile map (R6: FETCH ~49 MB): XCD gets an 8x8 macro-tile
  const int orig = blockIdx.x;
  const int macro = orig & 7;
  const int mj = orig >> 3;                // 0..63
  const int bm = ((macro >> 1) * 8 + (mj >> 3)) * 256;   // 32 M-tiles
  const int bn = ((macro & 1) * 8 + (mj & 7)) * 256;     // 16 N-tiles

  // staging: thread covers row rid (+64j), LDS chunk-slot tid&7,
  // logical chunk cst = (tid&7) ^ (rid&7)
  const int rid = tid >> 3;
  const int cst = (tid & 7) ^ (rid & 7);
  const unsigned short* Asrc = A + (size_t)(bm + rid) * K + cst * 8;
  const unsigned short* Bsrc = B + (size_t)(bn + rid) * K + cst * 8;

  // fragment read swizzle: r&7 == fl&7 for all frag rows
  const int swk0 = (hi ^ (fl & 7)) * 8;        // kk=0 (chunk hi)
  const int swk1 = ((4 + hi) ^ (fl & 7)) * 8;  // kk=1 (chunk 4+hi)
  const int arow = (wm * 128 + fl) * 64;
  const int brow = (wn * 64 + fl) * 64;

  f32x4 acc[8][4];
#pragma unroll
  for (int m = 0; m < 8; m++)
#pragma unroll
    for (int n = 0; n < 4; n++) acc[m][n] = (f32x4){0.f, 0.f, 0.f, 0.f};

  short8 a[4][2], b0[2][2], b1[2][2];

#define STAGE_A(s, h, kt)                                                      \
  do {                                                                         \
    gload16(Asrc + (size_t)((h) * 128) * K + (kt) * 64,                        \
            &lds[(s) * SLOT + (((h) * 2) * 512 + tid) * 8]);                   \
    gload16(Asrc + (size_t)((h) * 128 + 64) * K + (kt) * 64,                   \
            &lds[(s) * SLOT + (((h) * 2 + 1) * 512 + tid) * 8]);               \
  } while (0)
#define STAGE_B(s, h, kt)                                                      \
  do {                                                                         \
    gload16(Bsrc + (size_t)((h) * 128) * K + (kt) * 64,                        \
            &lds[(s) * SLOT + BOFF + (((h) * 2) * 512 + tid) * 8]);            \
    gload16(Bsrc + (size_t)((h) * 128 + 64) * K + (kt) * 64,                   \
            &lds[(s) * SLOT + BOFF + (((h) * 2 + 1) * 512 + tid) * 8]);        \
  } while (0)
#define LDA(qm)                                                                \
  _Pragma("unroll") for (int m = 0; m < 4; m++) {                              \
    a[m][0] = *(const short8*)&Aslot[arow + (qm) * 4096 + m * 1024 + swk0];    \
    a[m][1] = *(const short8*)&Aslot[arow + (qm) * 4096 + m * 1024 + swk1];    \
  }
#define LDB(dst, qn)                                                           \
  _Pragma("unroll") for (int n = 0; n < 2; n++) {                              \
    dst[n][0] = *(const short8*)&Bslot[brow + (qn) * 2048 + n * 1024 + swk0];  \
    dst[n][1] = *(const short8*)&Bslot[brow + (qn) * 2048 + n * 1024 + swk1];  \
  }
#define MFMA16(qm, qn, bb)                                                     \
  __builtin_amdgcn_s_setprio(1);                                               \
  _Pragma("unroll") for (int m = 0; m < 4; m++)                                \
  _Pragma("unroll") for (int n = 0; n < 2; n++)                                \
  _Pragma("unroll") for (int kk = 0; kk < 2; kk++)                             \
    acc[(qm) * 4 + m][(qn) * 2 + n] = __builtin_amdgcn_mfma_f32_16x16x32_bf16( \
        a[m][kk], bb[n][kk], acc[(qm) * 4 + m][(qn) * 2 + n], 0, 0, 0);        \
  __builtin_amdgcn_s_setprio(0);
#define BAR1() __builtin_amdgcn_s_barrier();                                   \
  asm volatile("s_waitcnt lgkmcnt(0)" ::: "memory");                           \
  __builtin_amdgcn_sched_barrier(0)
#define BAR2() __builtin_amdgcn_s_barrier(); __builtin_amdgcn_sched_barrier(0)

  // prologue: tile0 fully + tile1 B halves; wait tile0 (allow tile1 B in flight)
  STAGE_A(0, 0, 0); STAGE_A(0, 1, 0);
  STAGE_B(0, 0, 0); STAGE_B(0, 1, 0);
  STAGE_B(1, 0, 1); STAGE_B(1, 1, 1);
  asm volatile("s_waitcnt vmcnt(4)" ::: "memory");
  __builtin_amdgcn_s_barrier();
  __builtin_amdgcn_sched_barrier(0);

  for (int t = 0; t < NT; ++t) {
    const unsigned short* Aslot = &lds[(t & 1) * SLOT];
    const unsigned short* Bslot = Aslot + BOFF;
    // ---- phase 0: (qm0,qn0); stage A-half0(t+1) ----
    LDA(0); LDB(b0, 0);
    if (t + 1 < NT) STAGE_A((t + 1) & 1, 0, t + 1);
    BAR1();
    MFMA16(0, 0, b0);
    BAR2();
    // ---- phase 1: (qm0,qn1); stage A-half1(t+1) ----
    LDB(b1, 1);
    if (t + 1 < NT) STAGE_A((t + 1) & 1, 1, t + 1);
    BAR1();
    MFMA16(0, 1, b1);
    BAR2();
    // ---- phase 2: (qm1,qn1); stage B-half0(t+2) ----
    LDA(1);
    if (t + 2 < NT) STAGE_B(t & 1, 0, t + 2);
    BAR1();
    MFMA16(1, 1, b1);
    BAR2();
    // ---- phase 3: (qm1,qn0); stage B-half1(t+2); vmcnt(4) ----
    if (t + 2 < NT) STAGE_B(t & 1, 1, t + 2);
    __builtin_amdgcn_s_barrier();
    __builtin_amdgcn_sched_barrier(0);
    MFMA16(1, 0, b0);
    if (t + 2 < NT) {
      asm volatile("s_waitcnt vmcnt(4)" ::: "memory");
    } else if (t + 1 < NT) {
      asm volatile("s_waitcnt vmcnt(0)" ::: "memory");
    }
    if (t + 1 < NT) { BAR2(); }
  }
#undef STAGE_A
#undef STAGE_B
#undef LDA
#undef LDB
#undef MFMA16
#undef BAR1
#undef BAR2

  // ---- epilogue: C/D layout col=lane&15, row=(lane>>4)*4+j ----
  float bv[4];
#pragma unroll
  for (int n = 0; n < 4; n++) bv[n] = bias[bn + wn * 64 + n * 16 + fl];
#pragma unroll
  for (int m = 0; m < 8; m++) {
    const int gr0 = bm + wm * 128 + m * 16 + hi * 4;
#pragma unroll
    for (int n = 0; n < 4; n++) {
      const int gc = bn + wn * 64 + n * 16 + fl;
#pragma unroll
      for (int jj = 0; jj < 4; jj++)
        C[(size_t)(gr0 + jj) * N + gc] = acc[m][n][jj] + bv[n];
    }
  }
}

// ---------------- launcher ----------------
extern "C" void kernel_launch(void* const* d_in, const int* in_sizes, int n_in,
                              void* d_out, int out_size, void* d_ws, size_t ws_size,
                              hipStream_t stream) {
  const float* x      = (const float*)d_in[0];
  const float* embed  = (const float*)d_in[1];
  const float* base_w = (const float*)d_in[2];
  const float* base_b = (const float*)d_in[3];
  const float* lrf    = (const float*)d_in[4];
  const float* w1     = (const float*)d_in[5];
  const float* b1     = (const float*)d_in[6];
  const float* w2     = (const float*)d_in[7];
  const float* b2     = (const float*)d_in[8];
  float* out = (float*)d_out;

  char* ws = (char*)d_ws;
  unsigned short* Xbf = (unsigned short*)ws;                              // 16 MB
  unsigned short* Wbf = (unsigned short*)(ws + (size_t)BATCH_M * MAX_IN * 2);  // 8 MB

  hipLaunchKernelGGL(convert_x, dim3(BATCH_M * MAX_IN / 1024), dim3(256), 0, stream, x, Xbf);
  hipLaunchKernelGGL(build_w_fused, dim3(MAX_OUT / 8), dim3(256), 0, stream,
                     w1, b1, embed, w2, b2, base_w, lrf, Wbf);
  hipLaunchKernelGGL(gemm_kernel, dim3((BATCH_M / 256) * (MAX_OUT / 256)), dim3(512), 0, stream,
                     Xbf, Wbf, base_b, out);
}